// Round 15
// baseline (1646.337 us; speedup 1.0000x reference)
//
#include <hip/hip_runtime.h>
#include <hip/hip_bf16.h>

#define T_TOK 4096
#define HDIM  1024
#define NEXP  8
#define IDIM  1408
#define ISDIM 2816
#define PADT  9216    // 72 tiles of 128 (worst-case padded expert rows)

typedef short bf16x8 __attribute__((ext_vector_type(8)));
typedef float f32x4  __attribute__((ext_vector_type(4)));
typedef unsigned short u16;
typedef unsigned short u16x4 __attribute__((ext_vector_type(4)));
typedef unsigned short u16x8 __attribute__((ext_vector_type(8)));

typedef __attribute__((address_space(1))) const void gvoid;
typedef __attribute__((address_space(3))) void lvoid;

__device__ __forceinline__ u16 f2bf(float f) {
    union { float f; unsigned u; } c; c.f = f;
    unsigned r = (c.u + 0x7FFFu + ((c.u >> 16) & 1u)) >> 16;
    return (u16)r;
}
__device__ __forceinline__ float bf2f(u16 v) {
    union { unsigned u; float f; } c; c.u = (unsigned)v << 16; return c.f;
}
__device__ __forceinline__ void glds16(const u16* g, u16* l) {
    __builtin_amdgcn_global_load_lds((gvoid*)g, (lvoid*)l, 16, 0, 0);
}

// ---------------- routing: one wave per token (no atomics) ----------------
__global__ __launch_bounds__(256) void route_kernel(
    const float* __restrict__ X, const float* __restrict__ GW,
    const float* __restrict__ SEG,
    int* __restrict__ topk_e, float* __restrict__ topk_w,
    float* __restrict__ sgate)
{
    const int t = blockIdx.x * 4 + (threadIdx.x >> 6);
    const int lane = threadIdx.x & 63;
    float acc[NEXP];
    #pragma unroll
    for (int e = 0; e < NEXP; ++e) acc[e] = 0.f;
    float sacc = 0.f;
    const float* xr = X + (size_t)t * HDIM;
    for (int h = lane; h < HDIM; h += 64) {
        float xv = xr[h];
        f32x4 g0 = *(const f32x4*)(GW + (size_t)h * NEXP);
        f32x4 g1 = *(const f32x4*)(GW + (size_t)h * NEXP + 4);
        acc[0] += xv * g0[0]; acc[1] += xv * g0[1];
        acc[2] += xv * g0[2]; acc[3] += xv * g0[3];
        acc[4] += xv * g1[0]; acc[5] += xv * g1[1];
        acc[6] += xv * g1[2]; acc[7] += xv * g1[3];
        sacc += xv * SEG[h];
    }
    #pragma unroll
    for (int off = 32; off > 0; off >>= 1) {
        #pragma unroll
        for (int e = 0; e < NEXP; ++e) acc[e] += __shfl_down(acc[e], off);
        sacc += __shfl_down(sacc, off);
    }
    if (lane == 0) {
        int e0 = 0;
        #pragma unroll
        for (int e = 1; e < NEXP; ++e) if (acc[e] > acc[e0]) e0 = e;
        int e1 = (e0 == 0) ? 1 : 0;
        #pragma unroll
        for (int e = 0; e < NEXP; ++e)
            if (e != e0 && acc[e] > acc[e1]) e1 = e;
        float w0 = 1.f / (1.f + __expf(acc[e1] - acc[e0]));
        topk_e[t * 2]     = e0; topk_e[t * 2 + 1] = e1;
        topk_w[t * 2]     = w0; topk_w[t * 2 + 1] = 1.f - w0;
        sgate[t] = 1.f / (1.f + __expf(-sacc));
    }
}

// ---------------- histogram (+ tok_ids prefill) ----------------
__global__ __launch_bounds__(256) void hist_kernel(
    const int* __restrict__ topk_e, int* __restrict__ counts,
    int* __restrict__ tok_ids)
{
    __shared__ int h[NEXP];
    if (threadIdx.x < NEXP) h[threadIdx.x] = 0;
    __syncthreads();
    int i = blockIdx.x * 256 + threadIdx.x;
    atomicAdd(&h[topk_e[i]], 1);
    for (int j = i; j < PADT; j += gridDim.x * 256) tok_ids[j] = 0;
    __syncthreads();
    if (threadIdx.x < NEXP) atomicAdd(&counts[threadIdx.x], h[threadIdx.x]);
}

// seg_pad[e]: 128-aligned padded segment starts; seg_pad[8] = padded total
__global__ void offsets_kernel(const int* __restrict__ counts,
                               int* __restrict__ seg_pad,
                               int* __restrict__ cursors)
{
    if (threadIdx.x == 0) {
        int s = 0;
        for (int e = 0; e < NEXP; ++e) {
            seg_pad[e] = s; cursors[e] = s;
            s += ((counts[e] + 127) >> 7) << 7;
        }
        seg_pad[NEXP] = s;
    }
}

// ---------------- scatter ----------------
__global__ __launch_bounds__(256) void scatter_kernel(
    const int* __restrict__ topk_e,
    int* __restrict__ cursors, int* __restrict__ tok_ids,
    int* __restrict__ slot)
{
    const int i = blockIdx.x * 256 + threadIdx.x;
    const int lane = threadIdx.x & 63;
    const int e = topk_e[i];
    const unsigned long long lt = (1ull << lane) - 1ull;
    #pragma unroll
    for (int ex = 0; ex < NEXP; ++ex) {
        unsigned long long mask = __ballot(e == ex);
        if (mask == 0ull) continue;
        int cnt = __popcll(mask);
        int leader = __ffsll((long long)mask) - 1;
        int base_ = 0;
        if (lane == leader) base_ = atomicAdd(&cursors[ex], cnt);
        base_ = __shfl(base_, leader);
        if (e == ex) {
            int pos = base_ + __popcll(mask & lt);
            tok_ids[pos] = i >> 1;
            slot[i] = pos;
        }
    }
}

// ---------------- converts ----------------
__global__ __launch_bounds__(256) void cvt_x_kernel(
    const float* __restrict__ in, u16* __restrict__ out, int n)
{
    int i = (blockIdx.x * 256 + threadIdx.x) * 8;
    if (i < n) {
        f32x4 a = *(const f32x4*)(in + i);
        f32x4 b = *(const f32x4*)(in + i + 4);
        u16x8 o;
        #pragma unroll
        for (int j = 0; j < 4; ++j) { o[j] = f2bf(a[j]); o[j + 4] = f2bf(b[j]); }
        *(u16x8*)(out + i) = o;
    }
}

// fp32 [K][N] slices -> bf16 [N][K] (ilv=0) or 16-row gate/up interleave (ilv=1)
__global__ __launch_bounds__(256) void transpose_cvt(
    const float* __restrict__ in0, const float* __restrict__ in1,
    u16* __restrict__ out, int K, int N, int split, int ilv)
{
    const int z = blockIdx.z;
    const int e = (z < split) ? z : z - split;
    const float* in = (z < split) ? (in0 + (size_t)z * K * N)
                                  : (in1 + (size_t)(z - split) * K * N);
    u16* o = ilv ? (out + (size_t)e * 2 * N * K)
                 : (out + (size_t)z * N * K);
    const int radd = ilv ? ((z < split) ? 0 : 16) : 0;

    __shared__ float tile[64][65];
    const int n0 = blockIdx.x * 64, k0 = blockIdx.y * 64;
    const int tx = threadIdx.x & 15;
    const int ty = threadIdx.x >> 4;

    #pragma unroll
    for (int p = 0; p < 4; ++p) {
        int k = ty + p * 16;
        f32x4 v = *(const f32x4*)(in + (size_t)(k0 + k) * N + n0 + tx * 4);
        *(f32x4*)&tile[k][tx * 4] = v;
    }
    __syncthreads();
    const int kb = (threadIdx.x & 7) * 8;
    const int nr = threadIdx.x >> 3;   // 0..31
    #pragma unroll
    for (int p = 0; p < 2; ++p) {
        int n = nr + p * 32;
        u16x8 w;
        #pragma unroll
        for (int j = 0; j < 8; ++j) w[j] = f2bf(tile[kb + j][n]);
        int R = n0 + n;
        int orow = ilv ? (((R >> 4) * 32) + (R & 15) + radd) : R;
        *(u16x8*)(o + (size_t)orow * K + k0 + kb) = w;
    }
}

// ===== 128M x 256N x BK32, 8 waves (512 thr, wave tile 64x64), dbuf, 1 barrier/tile =====
// LDS: A [2 buf][128 rows][32 k] = 16KB, B [2 buf][256 rows][32 k] = 32KB (48KB dyn).
// Granule swizzle (verified 0-conflict): slot (row, s) holds granule s^((row>>1)&3).
//   Stage: dest linear tid*16B; source k-granule ((tid&3)^((tid>>3)&3)).  (row+128
//   keeps the same parity bits, so the same sk works for B's second row.)
//   Read:  u16 offset row*32 + ((ksl^((l15>>1)&3))*8).

#define BAR() __builtin_amdgcn_s_barrier()
#define WCNT0() asm volatile("s_waitcnt vmcnt(0)" ::: "memory")

#define GSTAGE(ab, bb) do { \
    glds16(aP,  &As[(ab) + tid * 8]); \
    glds16(bP0, &Bs[(bb) + tid * 8]); \
    glds16(bP1, &Bs[(bb) + 4096 + tid * 8]); \
    aP += 32; bP0 += 32; bP1 += 32; } while (0)

#define GEMM_TILE(ra, rb) { \
    bf16x8 av[4], bv[4]; \
    _Pragma("unroll") for (int q = 0; q < 4; ++q) bv[q] = *(const bf16x8*)&Bs[(rb) + bofs[q]]; \
    _Pragma("unroll") for (int q = 0; q < 4; ++q) av[q] = *(const bf16x8*)&As[(ra) + aofs[q]]; \
    __builtin_amdgcn_s_setprio(1); \
    _Pragma("unroll") for (int q = 0; q < 4; ++q) \
        _Pragma("unroll") for (int w = 0; w < 4; ++w) \
            acc[q][w] = __builtin_amdgcn_mfma_f32_16x16x32_bf16(av[q], bv[w], acc[q][w], 0, 0, 0); \
    __builtin_amdgcn_s_setprio(0); }

#define GEMM_MAIN(NT) \
    GSTAGE(0, 0); \
    _Pragma("unroll 1") \
    for (int t = 0; t < (NT) - 1; ++t) { \
        WCNT0(); BAR(); \
        GSTAGE((t & 1) ? 0 : 4096, (t & 1) ? 0 : 8192); \
        GEMM_TILE((t & 1) * 4096, (t & 1) * 8192) \
    } \
    WCNT0(); BAR(); \
    GEMM_TILE((((NT) - 1) & 1) * 4096, (((NT) - 1) & 1) * 8192)

// ---------------- merged gate+up GEMM (interleaved combined weights [2N][K]) ----------------
// grid(1496): zz<792 expert (widx=zz/11 m-tile of 128, nz=zz%11; exit if past seg_pad[8]);
// zz>=792 shared (sidx: m=sidx/22 of 32, n=sidx%22)
__global__ __launch_bounds__(512, 6) void gemm_gu(
    const u16* __restrict__ A,
    const u16* __restrict__ WGUc, const u16* __restrict__ SGUc,
    u16* __restrict__ HoutE, u16* __restrict__ HoutS,
    const int* __restrict__ tok_ids, const int* __restrict__ seg_pad)
{
    extern __shared__ u16 lds[];
    u16* As = lds;
    u16* Bs = lds + 8192;

    const int zz = blockIdx.x;
    int m0, nblk, N;
    const u16* Bsrc;
    u16* Hout;
    bool gather;
    if (zz < 792) {
        int widx = zz / 11;
        nblk = zz - widx * 11;
        m0 = widx * 128;
        if (m0 >= seg_pad[NEXP]) return;
        int e = 0;
        while (e < 7 && m0 >= seg_pad[e + 1]) ++e;
        Bsrc = WGUc + (size_t)e * (2 * IDIM * HDIM);
        Hout = HoutE; N = IDIM; gather = true;
    } else {
        int sidx = zz - 792;
        int mz = sidx / 22;
        nblk = sidx - mz * 22;
        m0 = mz * 128;
        Bsrc = SGUc; Hout = HoutS; N = ISDIM; gather = false;
    }

    const int tid = threadIdx.x;
    const int srow = tid >> 2;                         // 0..127
    const int sk = (((tid & 3) ^ ((tid >> 3) & 3))) * 8;
    const int arow = m0 + srow;
    const int ga = gather ? tok_ids[arow] : arow;
    const u16* aP  = A + (size_t)ga * HDIM + sk;
    const u16* bP0 = Bsrc + (size_t)(nblk * 256 + srow) * HDIM + sk;
    const u16* bP1 = Bsrc + (size_t)(nblk * 256 + 128 + srow) * HDIM + sk;

    f32x4 acc[4][4];
    #pragma unroll
    for (int i = 0; i < 4; ++i)
        #pragma unroll
        for (int j = 0; j < 4; ++j) acc[i][j] = (f32x4){0.f, 0.f, 0.f, 0.f};

    const int lane = tid & 63;
    const int wv = tid >> 6;
    const int wr = wv >> 2;        // 0..1  (m)
    const int wn = wv & 3;         // 0..3  (n)
    const int l15 = lane & 15;
    const int ksl = lane >> 4;
    const int kswz = ((ksl ^ ((l15 >> 1) & 3))) * 8;
    int aofs[4], bofs[4];
    #pragma unroll
    for (int q = 0; q < 4; ++q) {
        aofs[q] = (wr * 64 + q * 16 + l15) * 32 + kswz;
        bofs[q] = (wn * 64 + q * 16 + l15) * 32 + kswz;
    }

    GEMM_MAIN(32)   // K = 1024

    const int l4 = ksl * 4;
    #pragma unroll
    for (int j = 0; j < 4; ++j)
        #pragma unroll
        for (int p = 0; p < 2; ++p) {
            f32x4 g = acc[j][2 * p], u = acc[j][2 * p + 1];
            int c = nblk * 128 + (wn * 2 + p) * 16 + l15;
            #pragma unroll
            for (int jj = 0; jj < 4; ++jj) {
                int r = m0 + wr * 64 + j * 16 + l4 + jj;
                float hv = g[jj] / (1.f + __expf(-g[jj])) * u[jj];
                Hout[(size_t)r * N + c] = f2bf(hv);
            }
        }
}

// ---------------- down GEMM: grid(544) ----------------
// zz<288: expert (widx=zz>>2 m-tile of 128, n=(zz&3)*256; exit past seg_pad[8]) -> store Dexp
// zz>=288: shared (idx: kc=idx>>7, m=(idx&127)>>2 of 32, n=idx&3) -> atomicAdd Out
// Both paths: K-chunk = 1408 = 44 x 32 -> NT = 44.
__global__ __launch_bounds__(512, 6) void gemm_down(
    const u16* __restrict__ AE, const u16* __restrict__ AS,
    const u16* __restrict__ WDt, const u16* __restrict__ SDt,
    float* __restrict__ DexpO, float* __restrict__ OutS,
    const int* __restrict__ seg_pad)
{
    extern __shared__ u16 lds[];
    u16* As = lds;
    u16* Bs = lds + 8192;

    const int zz = blockIdx.x;
    const bool shr = (zz >= 288);
    int m0, n0, kst;
    size_t koff;
    const u16 *Asrc, *Bsrc;
    if (!shr) {
        int widx = zz >> 2;
        n0 = (zz & 3) * 256;
        m0 = widx * 128;
        if (m0 >= seg_pad[NEXP]) return;
        int e = 0;
        while (e < 7 && m0 >= seg_pad[e + 1]) ++e;
        Asrc = AE; Bsrc = WDt + (size_t)e * (HDIM * IDIM);
        kst = IDIM; koff = 0;
    } else {
        int idx = zz - 288;        // 0..255
        int kc = idx >> 7;         // 0..1
        int rem = idx & 127;
        m0 = (rem >> 2) * 128;     // 32 m-tiles
        n0 = (rem & 3) * 256;
        Asrc = AS; Bsrc = SDt;
        kst = ISDIM; koff = (size_t)kc * 1408;
    }

    const int tid = threadIdx.x;
    const int srow = tid >> 2;
    const int sk = (((tid & 3) ^ ((tid >> 3) & 3))) * 8;
    const u16* aP  = Asrc + (size_t)(m0 + srow) * kst + koff + sk;
    const u16* bP0 = Bsrc + (size_t)(n0 + srow) * kst + koff + sk;
    const u16* bP1 = Bsrc + (size_t)(n0 + 128 + srow) * kst + koff + sk;

    f32x4 acc[4][4];
    #pragma unroll
    for (int i = 0; i < 4; ++i)
        #pragma unroll
        for (int j = 0; j < 4; ++j) acc[i][j] = (f32x4){0.f, 0.f, 0.f, 0.f};

    const int lane = tid & 63;
    const int wv = tid >> 6;
    const int wr = wv >> 2;
    const int wn = wv & 3;
    const int l15 = lane & 15;
    const int ksl = lane >> 4;
    const int kswz = ((ksl ^ ((l15 >> 1) & 3))) * 8;
    int aofs[4], bofs[4];
    #pragma unroll
    for (int q = 0; q < 4; ++q) {
        aofs[q] = (wr * 64 + q * 16 + l15) * 32 + kswz;
        bofs[q] = (wn * 64 + q * 16 + l15) * 32 + kswz;
    }

    GEMM_MAIN(44)   // K-chunk = 1408 for BOTH paths (44 x 32)

    const int l4 = ksl * 4;
    #pragma unroll
    for (int j = 0; j < 4; ++j)
        #pragma unroll
        for (int i = 0; i < 4; ++i) {
            int c = n0 + wn * 64 + i * 16 + l15;
            #pragma unroll
            for (int jj = 0; jj < 4; ++jj) {
                int r = m0 + wr * 64 + j * 16 + l4 + jj;
                if (!shr)
                    DexpO[(size_t)r * HDIM + c] = acc[j][i][jj];
                else
                    atomicAdd(&OutS[(size_t)r * HDIM + c], acc[j][i][jj]);
            }
        }
}

// ---------------- combine ----------------
__global__ __launch_bounds__(256) void combine_kernel(
    const float* __restrict__ Dexp,
    const int* __restrict__ slot, const float* __restrict__ topk_w,
    const float* __restrict__ sgate, float* __restrict__ Out)
{
    int idx = blockIdx.x * 256 + threadIdx.x;
    int t = idx >> 8;
    int c = (idx & 255) * 4;
    int s0 = slot[2 * t], s1 = slot[2 * t + 1];
    float w0 = topk_w[2 * t], w1 = topk_w[2 * t + 1], sg = sgate[t];
    f32x4 sh = *(const f32x4*)(Out + (size_t)t * HDIM + c);
    f32x4 d0 = *(const f32x4*)(Dexp + (size_t)s0 * HDIM + c);
    f32x4 d1 = *(const f32x4*)(Dexp + (size_t)s1 * HDIM + c);
    f32x4 o;
    #pragma unroll
    for (int j = 0; j < 4; ++j) o[j] = sg * sh[j] + w0 * d0[j] + w1 * d1[j];
    *(f32x4*)(Out + (size_t)t * HDIM + c) = o;
}

// ---------------- launch ----------------
extern "C" void kernel_launch(void* const* d_in, const int* in_sizes, int n_in,
                              void* d_out, int out_size, void* d_ws, size_t ws_size,
                              hipStream_t stream)
{
    const float* X   = (const float*)d_in[0];
    const float* GW  = (const float*)d_in[1];
    const float* WG  = (const float*)d_in[2];
    const float* WU  = (const float*)d_in[3];
    const float* WD  = (const float*)d_in[4];
    const float* SG  = (const float*)d_in[5];
    const float* SU  = (const float*)d_in[6];
    const float* SD  = (const float*)d_in[7];
    const float* SEG = (const float*)d_in[8];
    float* Out = (float*)d_out;

    char* ws = (char*)d_ws;
    int*   counts    = (int*)(ws + 0);
    int*   seg_pad   = (int*)(ws + 64);
    int*   cursors   = (int*)(ws + 128);
    int*   topk_e    = (int*)(ws + 1024);
    float* topk_w    = (float*)(ws + 1024 + 32768);
    float* sgate     = (float*)(ws + 1024 + 65536);
    int*   slot      = (int*)(ws + 1024 + 65536 + 16384);
    int*   tok_ids   = (int*)(ws + 1024 + 65536 + 16384 + 32768);   // 9216 ints

    u16* Xbf  = (u16*)(ws + 0x0040000ull);   // 8.39 MB
    u16* Hact = (u16*)(ws + 0x0840000ull);   // 9216x1408 bf16 = 26 MB
    u16* Hs   = (u16*)(ws + 0x23C0000ull);   // 4096x2816 bf16 = 23.1 MB
    u16* WGUc = (u16*)(ws + 0x39C0000ull);   // 8 x ilv [2816][1024] = 46.1 MB
    u16* WDt  = (u16*)(ws + 0x65C0000ull);   // 8 x [1024][1408] = 23.1 MB
    u16* SGUc = (u16*)(ws + 0x7BC0000ull);   // ilv [5632][1024] = 11.5 MB
    u16* SDt  = (u16*)(ws + 0x86C0000ull);   // [1024][2816] = 5.8 MB
    // Dexp (9216x1024 f32 = 37.7 MB) aliases WGUc (46.1 MB), written after gemm_gu
    float* Dexp = (float*)(ws + 0x39C0000ull);

    hipMemsetAsync(counts, 0, 64, stream);
    hipMemsetAsync(Out, 0, (size_t)T_TOK * HDIM * sizeof(float), stream);

    // routing
    route_kernel<<<T_TOK / 4, 256, 0, stream>>>(X, GW, SEG, topk_e, topk_w, sgate);
    hist_kernel<<<(T_TOK * 2) / 256, 256, 0, stream>>>(topk_e, counts, tok_ids);
    offsets_kernel<<<1, 64, 0, stream>>>(counts, seg_pad, cursors);
    scatter_kernel<<<(T_TOK * 2) / 256, 256, 0, stream>>>(topk_e, cursors, tok_ids, slot);

    // converts
    cvt_x_kernel<<<(T_TOK * HDIM) / (256 * 8), 256, 0, stream>>>(X, Xbf, T_TOK * HDIM);
    transpose_cvt<<<dim3(IDIM / 64, HDIM / 64, 2 * NEXP), 256, 0, stream>>>(WG, WU, WGUc, HDIM, IDIM, NEXP, 1);
    transpose_cvt<<<dim3(HDIM / 64, IDIM / 64, NEXP), 256, 0, stream>>>(WD, WD, WDt, IDIM, HDIM, NEXP, 0);
    transpose_cvt<<<dim3(ISDIM / 64, HDIM / 64, 2), 256, 0, stream>>>(SG, SU, SGUc, HDIM, ISDIM, 1, 1);
    transpose_cvt<<<dim3(HDIM / 64, ISDIM / 64, 1), 256, 0, stream>>>(SD, SD, SDt, ISDIM, HDIM, 1, 0);

    // merged gate+up: expert (<=72 m-tiles x 11 n) + shared (32 x 22)
    gemm_gu<<<1496, 512, 49152, stream>>>(
        Xbf, WGUc, SGUc, Hact, Hs, tok_ids, seg_pad);

    // merged down: expert (<=72 x 4) -> Dexp, shared (2 kc x 32 x 4) -> atomicAdd Out
    gemm_down<<<544, 512, 49152, stream>>>(
        Hact, Hs, WDt, SDt, Dexp, Out, seg_pad);

    // final combine
    combine_kernel<<<(T_TOK * HDIM / 4) / 256, 256, 0, stream>>>(
        Dexp, slot, topk_w, sgate, Out);
}

// Round 16
// 315.274 us; speedup vs baseline: 5.2219x; 5.2219x over previous
//
#include <hip/hip_runtime.h>
#include <hip/hip_bf16.h>

#define T_TOK 4096
#define HDIM  1024
#define NEXP  8
#define IDIM  1408
#define ISDIM 2816
#define PADT  9216    // 72 tiles of 128 (worst-case padded expert rows)

typedef short bf16x8 __attribute__((ext_vector_type(8)));
typedef float f32x4  __attribute__((ext_vector_type(4)));
typedef unsigned short u16;
typedef unsigned short u16x4 __attribute__((ext_vector_type(4)));
typedef unsigned short u16x8 __attribute__((ext_vector_type(8)));

typedef __attribute__((address_space(1))) const void gvoid;
typedef __attribute__((address_space(3))) void lvoid;

__device__ __forceinline__ u16 f2bf(float f) {
    union { float f; unsigned u; } c; c.f = f;
    unsigned r = (c.u + 0x7FFFu + ((c.u >> 16) & 1u)) >> 16;
    return (u16)r;
}
__device__ __forceinline__ float bf2f(u16 v) {
    union { unsigned u; float f; } c; c.u = (unsigned)v << 16; return c.f;
}
__device__ __forceinline__ void glds16(const u16* g, u16* l) {
    __builtin_amdgcn_global_load_lds((gvoid*)g, (lvoid*)l, 16, 0, 0);
}

// ---------------- routing: one wave per token (no atomics) ----------------
__global__ __launch_bounds__(256) void route_kernel(
    const float* __restrict__ X, const float* __restrict__ GW,
    const float* __restrict__ SEG,
    int* __restrict__ topk_e, float* __restrict__ topk_w,
    float* __restrict__ sgate)
{
    const int t = blockIdx.x * 4 + (threadIdx.x >> 6);
    const int lane = threadIdx.x & 63;
    float acc[NEXP];
    #pragma unroll
    for (int e = 0; e < NEXP; ++e) acc[e] = 0.f;
    float sacc = 0.f;
    const float* xr = X + (size_t)t * HDIM;
    for (int h = lane; h < HDIM; h += 64) {
        float xv = xr[h];
        f32x4 g0 = *(const f32x4*)(GW + (size_t)h * NEXP);
        f32x4 g1 = *(const f32x4*)(GW + (size_t)h * NEXP + 4);
        acc[0] += xv * g0[0]; acc[1] += xv * g0[1];
        acc[2] += xv * g0[2]; acc[3] += xv * g0[3];
        acc[4] += xv * g1[0]; acc[5] += xv * g1[1];
        acc[6] += xv * g1[2]; acc[7] += xv * g1[3];
        sacc += xv * SEG[h];
    }
    #pragma unroll
    for (int off = 32; off > 0; off >>= 1) {
        #pragma unroll
        for (int e = 0; e < NEXP; ++e) acc[e] += __shfl_down(acc[e], off);
        sacc += __shfl_down(sacc, off);
    }
    if (lane == 0) {
        int e0 = 0;
        #pragma unroll
        for (int e = 1; e < NEXP; ++e) if (acc[e] > acc[e0]) e0 = e;
        int e1 = (e0 == 0) ? 1 : 0;
        #pragma unroll
        for (int e = 0; e < NEXP; ++e)
            if (e != e0 && acc[e] > acc[e1]) e1 = e;
        float w0 = 1.f / (1.f + __expf(acc[e1] - acc[e0]));
        topk_e[t * 2]     = e0; topk_e[t * 2 + 1] = e1;
        topk_w[t * 2]     = w0; topk_w[t * 2 + 1] = 1.f - w0;
        sgate[t] = 1.f / (1.f + __expf(-sacc));
    }
}

// ---------------- histogram (+ tok_ids prefill) ----------------
__global__ __launch_bounds__(256) void hist_kernel(
    const int* __restrict__ topk_e, int* __restrict__ counts,
    int* __restrict__ tok_ids)
{
    __shared__ int h[NEXP];
    if (threadIdx.x < NEXP) h[threadIdx.x] = 0;
    __syncthreads();
    int i = blockIdx.x * 256 + threadIdx.x;
    atomicAdd(&h[topk_e[i]], 1);
    for (int j = i; j < PADT; j += gridDim.x * 256) tok_ids[j] = 0;
    __syncthreads();
    if (threadIdx.x < NEXP) atomicAdd(&counts[threadIdx.x], h[threadIdx.x]);
}

// seg_pad[e]: 128-aligned padded segment starts; seg_pad[8] = padded total
__global__ void offsets_kernel(const int* __restrict__ counts,
                               int* __restrict__ seg_pad,
                               int* __restrict__ cursors)
{
    if (threadIdx.x == 0) {
        int s = 0;
        for (int e = 0; e < NEXP; ++e) {
            seg_pad[e] = s; cursors[e] = s;
            s += ((counts[e] + 127) >> 7) << 7;
        }
        seg_pad[NEXP] = s;
    }
}

// ---------------- scatter ----------------
__global__ __launch_bounds__(256) void scatter_kernel(
    const int* __restrict__ topk_e,
    int* __restrict__ cursors, int* __restrict__ tok_ids,
    int* __restrict__ slot)
{
    const int i = blockIdx.x * 256 + threadIdx.x;
    const int lane = threadIdx.x & 63;
    const int e = topk_e[i];
    const unsigned long long lt = (1ull << lane) - 1ull;
    #pragma unroll
    for (int ex = 0; ex < NEXP; ++ex) {
        unsigned long long mask = __ballot(e == ex);
        if (mask == 0ull) continue;
        int cnt = __popcll(mask);
        int leader = __ffsll((long long)mask) - 1;
        int base_ = 0;
        if (lane == leader) base_ = atomicAdd(&cursors[ex], cnt);
        base_ = __shfl(base_, leader);
        if (e == ex) {
            int pos = base_ + __popcll(mask & lt);
            tok_ids[pos] = i >> 1;
            slot[i] = pos;
        }
    }
}

// ---------------- converts ----------------
__global__ __launch_bounds__(256) void cvt_x_kernel(
    const float* __restrict__ in, u16* __restrict__ out, int n)
{
    int i = (blockIdx.x * 256 + threadIdx.x) * 8;
    if (i < n) {
        f32x4 a = *(const f32x4*)(in + i);
        f32x4 b = *(const f32x4*)(in + i + 4);
        u16x8 o;
        #pragma unroll
        for (int j = 0; j < 4; ++j) { o[j] = f2bf(a[j]); o[j + 4] = f2bf(b[j]); }
        *(u16x8*)(out + i) = o;
    }
}

// fp32 [K][N] slices -> bf16 [N][K] (ilv=0) or 16-row gate/up interleave (ilv=1)
__global__ __launch_bounds__(256) void transpose_cvt(
    const float* __restrict__ in0, const float* __restrict__ in1,
    u16* __restrict__ out, int K, int N, int split, int ilv)
{
    const int z = blockIdx.z;
    const int e = (z < split) ? z : z - split;
    const float* in = (z < split) ? (in0 + (size_t)z * K * N)
                                  : (in1 + (size_t)(z - split) * K * N);
    u16* o = ilv ? (out + (size_t)e * 2 * N * K)
                 : (out + (size_t)z * N * K);
    const int radd = ilv ? ((z < split) ? 0 : 16) : 0;

    __shared__ float tile[64][65];
    const int n0 = blockIdx.x * 64, k0 = blockIdx.y * 64;
    const int tx = threadIdx.x & 15;
    const int ty = threadIdx.x >> 4;

    #pragma unroll
    for (int p = 0; p < 4; ++p) {
        int k = ty + p * 16;
        f32x4 v = *(const f32x4*)(in + (size_t)(k0 + k) * N + n0 + tx * 4);
        *(f32x4*)&tile[k][tx * 4] = v;
    }
    __syncthreads();
    const int kb = (threadIdx.x & 7) * 8;
    const int nr = threadIdx.x >> 3;   // 0..31
    #pragma unroll
    for (int p = 0; p < 2; ++p) {
        int n = nr + p * 32;
        u16x8 w;
        #pragma unroll
        for (int j = 0; j < 8; ++j) w[j] = f2bf(tile[kb + j][n]);
        int R = n0 + n;
        int orow = ilv ? (((R >> 4) * 32) + (R & 15) + radd) : R;
        *(u16x8*)(o + (size_t)orow * K + k0 + kb) = w;
    }
}

// ===== 128M x 256N x BK32, 8 waves (512 thr, wave tile 64x64), dbuf, 1 barrier/tile =====
// LDS: A [2 buf][128 rows][32 k] = 16KB, B [2 buf][256 rows][32 k] = 32KB (48KB dyn).
// Granule swizzle (verified 0-conflict): slot (row, s) holds granule s^((row>>1)&3).

#define BAR() __builtin_amdgcn_s_barrier()
#define WCNT0() asm volatile("s_waitcnt vmcnt(0)" ::: "memory")

#define GSTAGE(ab, bb) do { \
    glds16(aP,  &As[(ab) + tid * 8]); \
    glds16(bP0, &Bs[(bb) + tid * 8]); \
    glds16(bP1, &Bs[(bb) + 4096 + tid * 8]); \
    aP += 32; bP0 += 32; bP1 += 32; } while (0)

#define GEMM_TILE(ra, rb) { \
    bf16x8 av[4], bv[4]; \
    _Pragma("unroll") for (int q = 0; q < 4; ++q) bv[q] = *(const bf16x8*)&Bs[(rb) + bofs[q]]; \
    _Pragma("unroll") for (int q = 0; q < 4; ++q) av[q] = *(const bf16x8*)&As[(ra) + aofs[q]]; \
    __builtin_amdgcn_s_setprio(1); \
    _Pragma("unroll") for (int q = 0; q < 4; ++q) \
        _Pragma("unroll") for (int w = 0; w < 4; ++w) \
            acc[q][w] = __builtin_amdgcn_mfma_f32_16x16x32_bf16(av[q], bv[w], acc[q][w], 0, 0, 0); \
    __builtin_amdgcn_s_setprio(0); }

#define GEMM_MAIN(NT) \
    GSTAGE(0, 0); \
    _Pragma("unroll 1") \
    for (int t = 0; t < (NT) - 1; ++t) { \
        WCNT0(); BAR(); \
        GSTAGE((t & 1) ? 0 : 4096, (t & 1) ? 0 : 8192); \
        GEMM_TILE((t & 1) * 4096, (t & 1) * 8192) \
    } \
    WCNT0(); BAR(); \
    GEMM_TILE((((NT) - 1) & 1) * 4096, (((NT) - 1) & 1) * 8192)

// ---------------- merged gate+up GEMM (interleaved combined weights [2N][K]) ----------------
// grid(1496): zz<792 expert (widx=zz/11 m-tile of 128, nz=zz%11; exit if past seg_pad[8]);
// zz>=792 shared (sidx: m=sidx/22 of 32, n=sidx%22)
__global__ __launch_bounds__(512, 4) void gemm_gu(
    const u16* __restrict__ A,
    const u16* __restrict__ WGUc, const u16* __restrict__ SGUc,
    u16* __restrict__ HoutE, u16* __restrict__ HoutS,
    const int* __restrict__ tok_ids, const int* __restrict__ seg_pad)
{
    extern __shared__ u16 lds[];
    u16* As = lds;
    u16* Bs = lds + 8192;

    const int zz = blockIdx.x;
    int m0, nblk, N;
    const u16* Bsrc;
    u16* Hout;
    bool gather;
    if (zz < 792) {
        int widx = zz / 11;
        nblk = zz - widx * 11;
        m0 = widx * 128;
        if (m0 >= seg_pad[NEXP]) return;
        int e = 0;
        while (e < 7 && m0 >= seg_pad[e + 1]) ++e;
        Bsrc = WGUc + (size_t)e * (2 * IDIM * HDIM);
        Hout = HoutE; N = IDIM; gather = true;
    } else {
        int sidx = zz - 792;
        int mz = sidx / 22;
        nblk = sidx - mz * 22;
        m0 = mz * 128;
        Bsrc = SGUc; Hout = HoutS; N = ISDIM; gather = false;
    }

    const int tid = threadIdx.x;
    const int srow = tid >> 2;                         // 0..127
    const int sk = (((tid & 3) ^ ((tid >> 3) & 3))) * 8;
    const int arow = m0 + srow;
    const int ga = gather ? tok_ids[arow] : arow;
    const u16* aP  = A + (size_t)ga * HDIM + sk;
    const u16* bP0 = Bsrc + (size_t)(nblk * 256 + srow) * HDIM + sk;
    const u16* bP1 = Bsrc + (size_t)(nblk * 256 + 128 + srow) * HDIM + sk;

    f32x4 acc[4][4];
    #pragma unroll
    for (int i = 0; i < 4; ++i)
        #pragma unroll
        for (int j = 0; j < 4; ++j) acc[i][j] = (f32x4){0.f, 0.f, 0.f, 0.f};

    const int lane = tid & 63;
    const int wv = tid >> 6;
    const int wr = wv >> 2;        // 0..1  (m)
    const int wn = wv & 3;         // 0..3  (n)
    const int l15 = lane & 15;
    const int ksl = lane >> 4;
    const int kswz = ((ksl ^ ((l15 >> 1) & 3))) * 8;
    int aofs[4], bofs[4];
    #pragma unroll
    for (int q = 0; q < 4; ++q) {
        aofs[q] = (wr * 64 + q * 16 + l15) * 32 + kswz;
        bofs[q] = (wn * 64 + q * 16 + l15) * 32 + kswz;
    }

    GEMM_MAIN(32)   // K = 1024

    const int l4 = ksl * 4;
    #pragma unroll
    for (int j = 0; j < 4; ++j)
        #pragma unroll
        for (int p = 0; p < 2; ++p) {
            f32x4 g = acc[j][2 * p], u = acc[j][2 * p + 1];
            int c = nblk * 128 + (wn * 2 + p) * 16 + l15;
            #pragma unroll
            for (int jj = 0; jj < 4; ++jj) {
                int r = m0 + wr * 64 + j * 16 + l4 + jj;
                float hv = g[jj] / (1.f + __expf(-g[jj])) * u[jj];
                Hout[(size_t)r * N + c] = f2bf(hv);
            }
        }
}

// ---------------- down GEMM: grid(544) ----------------
// zz<288: expert (widx=zz>>2 m-tile of 128, n=(zz&3)*256; exit past seg_pad[8]) -> store Dexp
// zz>=288: shared (idx: kc=idx>>7, m=(idx&127)>>2 of 32, n=idx&3) -> atomicAdd Out
// Both paths: K-chunk = 1408 = 44 x 32 -> NT = 44.
__global__ __launch_bounds__(512, 4) void gemm_down(
    const u16* __restrict__ AE, const u16* __restrict__ AS,
    const u16* __restrict__ WDt, const u16* __restrict__ SDt,
    float* __restrict__ DexpO, float* __restrict__ OutS,
    const int* __restrict__ seg_pad)
{
    extern __shared__ u16 lds[];
    u16* As = lds;
    u16* Bs = lds + 8192;

    const int zz = blockIdx.x;
    const bool shr = (zz >= 288);
    int m0, n0, kst;
    size_t koff;
    const u16 *Asrc, *Bsrc;
    if (!shr) {
        int widx = zz >> 2;
        n0 = (zz & 3) * 256;
        m0 = widx * 128;
        if (m0 >= seg_pad[NEXP]) return;
        int e = 0;
        while (e < 7 && m0 >= seg_pad[e + 1]) ++e;
        Asrc = AE; Bsrc = WDt + (size_t)e * (HDIM * IDIM);
        kst = IDIM; koff = 0;
    } else {
        int idx = zz - 288;        // 0..255
        int kc = idx >> 7;         // 0..1
        int rem = idx & 127;
        m0 = (rem >> 2) * 128;     // 32 m-tiles
        n0 = (rem & 3) * 256;
        Asrc = AS; Bsrc = SDt;
        kst = ISDIM; koff = (size_t)kc * 1408;
    }

    const int tid = threadIdx.x;
    const int srow = tid >> 2;
    const int sk = (((tid & 3) ^ ((tid >> 3) & 3))) * 8;
    const u16* aP  = Asrc + (size_t)(m0 + srow) * kst + koff + sk;
    const u16* bP0 = Bsrc + (size_t)(n0 + srow) * kst + koff + sk;
    const u16* bP1 = Bsrc + (size_t)(n0 + 128 + srow) * kst + koff + sk;

    f32x4 acc[4][4];
    #pragma unroll
    for (int i = 0; i < 4; ++i)
        #pragma unroll
        for (int j = 0; j < 4; ++j) acc[i][j] = (f32x4){0.f, 0.f, 0.f, 0.f};

    const int lane = tid & 63;
    const int wv = tid >> 6;
    const int wr = wv >> 2;
    const int wn = wv & 3;
    const int l15 = lane & 15;
    const int ksl = lane >> 4;
    const int kswz = ((ksl ^ ((l15 >> 1) & 3))) * 8;
    int aofs[4], bofs[4];
    #pragma unroll
    for (int q = 0; q < 4; ++q) {
        aofs[q] = (wr * 64 + q * 16 + l15) * 32 + kswz;
        bofs[q] = (wn * 64 + q * 16 + l15) * 32 + kswz;
    }

    GEMM_MAIN(44)   // K-chunk = 1408 for BOTH paths (44 x 32)

    const int l4 = ksl * 4;
    #pragma unroll
    for (int j = 0; j < 4; ++j)
        #pragma unroll
        for (int i = 0; i < 4; ++i) {
            int c = n0 + wn * 64 + i * 16 + l15;
            #pragma unroll
            for (int jj = 0; jj < 4; ++jj) {
                int r = m0 + wr * 64 + j * 16 + l4 + jj;
                if (!shr)
                    DexpO[(size_t)r * HDIM + c] = acc[j][i][jj];
                else
                    atomicAdd(&OutS[(size_t)r * HDIM + c], acc[j][i][jj]);
            }
        }
}

// ---------------- combine ----------------
__global__ __launch_bounds__(256) void combine_kernel(
    const float* __restrict__ Dexp,
    const int* __restrict__ slot, const float* __restrict__ topk_w,
    const float* __restrict__ sgate, float* __restrict__ Out)
{
    int idx = blockIdx.x * 256 + threadIdx.x;
    int t = idx >> 8;
    int c = (idx & 255) * 4;
    int s0 = slot[2 * t], s1 = slot[2 * t + 1];
    float w0 = topk_w[2 * t], w1 = topk_w[2 * t + 1], sg = sgate[t];
    f32x4 sh = *(const f32x4*)(Out + (size_t)t * HDIM + c);
    f32x4 d0 = *(const f32x4*)(Dexp + (size_t)s0 * HDIM + c);
    f32x4 d1 = *(const f32x4*)(Dexp + (size_t)s1 * HDIM + c);
    f32x4 o;
    #pragma unroll
    for (int j = 0; j < 4; ++j) o[j] = sg * sh[j] + w0 * d0[j] + w1 * d1[j];
    *(f32x4*)(Out + (size_t)t * HDIM + c) = o;
}

// ---------------- launch ----------------
extern "C" void kernel_launch(void* const* d_in, const int* in_sizes, int n_in,
                              void* d_out, int out_size, void* d_ws, size_t ws_size,
                              hipStream_t stream)
{
    const float* X   = (const float*)d_in[0];
    const float* GW  = (const float*)d_in[1];
    const float* WG  = (const float*)d_in[2];
    const float* WU  = (const float*)d_in[3];
    const float* WD  = (const float*)d_in[4];
    const float* SG  = (const float*)d_in[5];
    const float* SU  = (const float*)d_in[6];
    const float* SD  = (const float*)d_in[7];
    const float* SEG = (const float*)d_in[8];
    float* Out = (float*)d_out;

    char* ws = (char*)d_ws;
    int*   counts    = (int*)(ws + 0);
    int*   seg_pad   = (int*)(ws + 64);
    int*   cursors   = (int*)(ws + 128);
    int*   topk_e    = (int*)(ws + 1024);
    float* topk_w    = (float*)(ws + 1024 + 32768);
    float* sgate     = (float*)(ws + 1024 + 65536);
    int*   slot      = (int*)(ws + 1024 + 65536 + 16384);
    int*   tok_ids   = (int*)(ws + 1024 + 65536 + 16384 + 32768);   // 9216 ints

    u16* Xbf  = (u16*)(ws + 0x0040000ull);   // 8.39 MB
    u16* Hact = (u16*)(ws + 0x0840000ull);   // 9216x1408 bf16 = 26 MB
    u16* Hs   = (u16*)(ws + 0x23C0000ull);   // 4096x2816 bf16 = 23.1 MB
    u16* WGUc = (u16*)(ws + 0x39C0000ull);   // 8 x ilv [2816][1024] = 46.1 MB
    u16* WDt  = (u16*)(ws + 0x65C0000ull);   // 8 x [1024][1408] = 23.1 MB
    u16* SGUc = (u16*)(ws + 0x7BC0000ull);   // ilv [5632][1024] = 11.5 MB
    u16* SDt  = (u16*)(ws + 0x86C0000ull);   // [1024][2816] = 5.8 MB
    // Dexp (9216x1024 f32 = 37.7 MB) aliases WGUc (46.1 MB), written after gemm_gu
    float* Dexp = (float*)(ws + 0x39C0000ull);

    hipMemsetAsync(counts, 0, 64, stream);
    hipMemsetAsync(Out, 0, (size_t)T_TOK * HDIM * sizeof(float), stream);

    // routing
    route_kernel<<<T_TOK / 4, 256, 0, stream>>>(X, GW, SEG, topk_e, topk_w, sgate);
    hist_kernel<<<(T_TOK * 2) / 256, 256, 0, stream>>>(topk_e, counts, tok_ids);
    offsets_kernel<<<1, 64, 0, stream>>>(counts, seg_pad, cursors);
    scatter_kernel<<<(T_TOK * 2) / 256, 256, 0, stream>>>(topk_e, cursors, tok_ids, slot);

    // converts
    cvt_x_kernel<<<(T_TOK * HDIM) / (256 * 8), 256, 0, stream>>>(X, Xbf, T_TOK * HDIM);
    transpose_cvt<<<dim3(IDIM / 64, HDIM / 64, 2 * NEXP), 256, 0, stream>>>(WG, WU, WGUc, HDIM, IDIM, NEXP, 1);
    transpose_cvt<<<dim3(HDIM / 64, IDIM / 64, NEXP), 256, 0, stream>>>(WD, WD, WDt, IDIM, HDIM, NEXP, 0);
    transpose_cvt<<<dim3(ISDIM / 64, HDIM / 64, 2), 256, 0, stream>>>(SG, SU, SGUc, HDIM, ISDIM, 1, 1);
    transpose_cvt<<<dim3(HDIM / 64, ISDIM / 64, 1), 256, 0, stream>>>(SD, SD, SDt, ISDIM, HDIM, 1, 0);

    // merged gate+up: expert (<=72 m-tiles x 11 n) + shared (32 x 22)
    gemm_gu<<<1496, 512, 49152, stream>>>(
        Xbf, WGUc, SGUc, Hact, Hs, tok_ids, seg_pad);

    // merged down: expert (<=72 x 4) -> Dexp, shared (2 kc x 32 x 4) -> atomicAdd Out
    gemm_down<<<544, 512, 49152, stream>>>(
        Hact, Hs, WDt, SDt, Dexp, Out, seg_pad);

    // final combine
    combine_kernel<<<(T_TOK * HDIM / 4) / 256, 256, 0, stream>>>(
        Dexp, slot, topk_w, sgate, Out);
}